// Round 3
// baseline (32.695 us; speedup 1.0000x reference)
//
#include <hip/hip_runtime.h>

// RoPE with position gather — INVERSE (scatter) formulation.
// x:    [B=4, H=16, S=2048, D=128] f32
// rope: [4096, 128, 128] f32 (only 2x2 rotation diagonals read)
// tp:   [2048] int32;  out[b,h,s,:] = rotate(x[b,h,p,:], angles(p)), p=tp[s]
//
// Instead of block-per-s (random-p READS), build the inverse map p -> {s}
// and go block-per-p: x reads are each-line-exactly-once ascending-p
// (streaming), duplicate-p rotations computed once, writes scatter (cheap).
//
// ws layout: [0, 8KB) counts[2048], [8KB, 8KB+512KB) lists[2048][64].

#define SEQL 2048
#define DK   128
#define NBH  64
#define KCAP 64   // max multiplicity of one position; P(>64) ~ 0 for 2048 draws

__global__ void build_inverse_kernel(const int* __restrict__ tp,
                                     int* __restrict__ counts,
                                     int* __restrict__ lists) {
    int s = blockIdx.x * blockDim.x + threadIdx.x;
    if (s >= SEQL) return;
    int p = tp[s];
    int slot = atomicAdd(&counts[p], 1);
    if (slot < KCAP) lists[p * KCAP + slot] = s;
}

__global__ __launch_bounds__(256) void rope_scatter_kernel(
        const float* __restrict__ x,
        const float* __restrict__ rope,
        float* __restrict__ out,
        const int* __restrict__ counts,
        const int* __restrict__ lists) {
    const int p = blockIdx.x;
    const int cnt = counts[p];
    if (cnt == 0) return;

    const int q = threadIdx.x & 31;   // float4-quad within 128-elem row
    const int g = threadIdx.x >> 5;   // bh group 0..7

    const float* rp = rope + (size_t)p * (DK * DK);
    const int i0 = q << 1;
    const float2 cs0 = *reinterpret_cast<const float2*>(rp + (size_t)258 * i0);
    const float2 cs1 = *reinterpret_cast<const float2*>(rp + (size_t)258 * (i0 + 1));

    const size_t slice = (size_t)SEQL * DK;       // 1 bh slice
    const size_t xq = (size_t)p * DK + (q << 2);

    // Rotate all 8 bh rows this thread owns, into statically-indexed regs.
    float4 o0, o1, o2, o3, o4, o5, o6, o7;
    {
        float4 xv;
        #define ROT(T, BH) \
            xv = *reinterpret_cast<const float4*>(x + (size_t)(BH) * slice + xq); \
            T.x = xv.x * cs0.x - xv.y * cs0.y; \
            T.y = xv.x * cs0.y + xv.y * cs0.x; \
            T.z = xv.z * cs1.x - xv.w * cs1.y; \
            T.w = xv.z * cs1.y + xv.w * cs1.x;
        ROT(o0, g +  0) ROT(o1, g +  8) ROT(o2, g + 16) ROT(o3, g + 24)
        ROT(o4, g + 32) ROT(o5, g + 40) ROT(o6, g + 48) ROT(o7, g + 56)
        #undef ROT
    }

    for (int j = 0; j < cnt; ++j) {
        const int s = lists[p * KCAP + j];        // wave-uniform
        float* ob = out + (size_t)s * DK + (q << 2);
        *reinterpret_cast<float4*>(ob + (size_t)(g +  0) * slice) = o0;
        *reinterpret_cast<float4*>(ob + (size_t)(g +  8) * slice) = o1;
        *reinterpret_cast<float4*>(ob + (size_t)(g + 16) * slice) = o2;
        *reinterpret_cast<float4*>(ob + (size_t)(g + 24) * slice) = o3;
        *reinterpret_cast<float4*>(ob + (size_t)(g + 32) * slice) = o4;
        *reinterpret_cast<float4*>(ob + (size_t)(g + 40) * slice) = o5;
        *reinterpret_cast<float4*>(ob + (size_t)(g + 48) * slice) = o6;
        *reinterpret_cast<float4*>(ob + (size_t)(g + 56) * slice) = o7;
    }
}

// ---- fallback (R2 kernel) if ws_size is too small ----
__global__ __launch_bounds__(256) void rope_gather_kernel(
        const float* __restrict__ x,
        const float* __restrict__ rope,
        const int* __restrict__ tp,
        float* __restrict__ out) {
    const int s = blockIdx.x;
    const int p = tp[s];
    const int q = threadIdx.x & 31;
    const int g = threadIdx.x >> 5;

    const float* rp = rope + (size_t)p * (DK * DK);
    const int i0 = q << 1;
    const float2 cs0 = *reinterpret_cast<const float2*>(rp + (size_t)258 * i0);
    const float2 cs1 = *reinterpret_cast<const float2*>(rp + (size_t)258 * (i0 + 1));

    const size_t rowstride = (size_t)SEQL * DK;
    const size_t xbase = (size_t)p * DK + (q << 2);
    const size_t obase = (size_t)s * DK + (q << 2);

    #pragma unroll
    for (int bh = g; bh < NBH; bh += 8) {
        const float4 xv = *reinterpret_cast<const float4*>(x + xbase + (size_t)bh * rowstride);
        float4 o;
        o.x = xv.x * cs0.x - xv.y * cs0.y;
        o.y = xv.x * cs0.y + xv.y * cs0.x;
        o.z = xv.z * cs1.x - xv.w * cs1.y;
        o.w = xv.z * cs1.y + xv.w * cs1.x;
        *reinterpret_cast<float4*>(out + obase + (size_t)bh * rowstride) = o;
    }
}

extern "C" void kernel_launch(void* const* d_in, const int* in_sizes, int n_in,
                              void* d_out, int out_size, void* d_ws, size_t ws_size,
                              hipStream_t stream) {
    const float* x    = (const float*)d_in[0];
    const float* rope = (const float*)d_in[1];
    const int*   tp   = (const int*)d_in[2];
    float*       out  = (float*)d_out;

    const size_t need = (size_t)SEQL * sizeof(int)            // counts
                      + (size_t)SEQL * KCAP * sizeof(int);    // lists
    if (ws_size < need) {
        rope_gather_kernel<<<SEQL, 256, 0, stream>>>(x, rope, tp, out);
        return;
    }

    int* counts = (int*)d_ws;
    int* lists  = counts + SEQL;

    hipMemsetAsync(counts, 0, SEQL * sizeof(int), stream);
    build_inverse_kernel<<<SEQL / 256, 256, 0, stream>>>(tp, counts, lists);
    rope_scatter_kernel<<<SEQL, 256, 0, stream>>>(x, rope, out, counts, lists);
}

// Round 5
// 31.099 us; speedup vs baseline: 1.0513x; 1.0513x over previous
//
#include <hip/hip_runtime.h>

// RoPE with position gather — cs-table + output-streaming formulation.
// x:    [B=4, H=16, S=2048, D=128] f32
// rope: [4096, 128, 128] f32 (only 2x2 rotation diagonals read)
// tp:   [2048] int32;  out[b,h,s,:] = rotate(x[b,h,p,:], angles(p)), p=tp[s]
//
// Kernel 1: cstab[s][i] = (cos,sin)(p=tp[s], i)   (1 MB, L2-resident)
// Kernel 2: flat over out in memory order -> writes perfectly streaming;
//   grid-stride of 8 iters lands on the SAME s each iter (stride is a
//   multiple of 2048 rows) so tp + cs are loaded once, 8 independent
//   gathered x-loads + 8 contiguous nontemporal stores.

#define SEQL 2048
#define DK   128
#define NBH  64            // B*H
#define BLK  256
#define NBLK 2048
#define ITER 8             // NBH*SEQL*(DK/4) / (NBLK*BLK)

typedef float vfloat4 __attribute__((ext_vector_type(4)));  // native vec for nt-store

__global__ void build_cs_kernel(const float* __restrict__ rope,
                                const int* __restrict__ tp,
                                float2* __restrict__ cstab) {
    int t = blockIdx.x * blockDim.x + threadIdx.x;   // t = s*64 + i
    int s = t >> 6, i = t & 63;
    int p = tp[s];
    cstab[t] = *reinterpret_cast<const float2*>(rope + (size_t)p * (DK * DK) + (size_t)258 * i);
}

__global__ __launch_bounds__(BLK) void rope_flat_kernel(
        const float* __restrict__ x,
        const float2* __restrict__ cstab,
        const int* __restrict__ tp,
        float* __restrict__ out) {
    const int idx0 = blockIdx.x * BLK + threadIdx.x;
    const int row0 = idx0 >> 5;            // bh*SEQL + s
    const int q    = idx0 & 31;            // float4-quad in row
    const int s    = row0 & (SEQL - 1);    // constant across iters
    const int bh0  = row0 >> 11;
    const int p    = tp[s];

    // (cos0, sin0, cos1, sin1) for pairs 2q, 2q+1 — 16B-aligned L2 load
    const float4 cs = *reinterpret_cast<const float4*>(cstab + (size_t)s * 64 + (q << 1));

    const size_t slice = (size_t)SEQL * DK;             // bh stride
    const float* xb = x + (size_t)p * DK + (q << 2);
    float* ob = out + (size_t)idx0 * 4;                 // contiguous per wave
    const size_t ostep = (size_t)NBLK * BLK * 4;        // 8 bh slices ahead

    #pragma unroll
    for (int k = 0; k < ITER; ++k) {
        const float4 xv = *reinterpret_cast<const float4*>(xb + (size_t)(bh0 + 8 * k) * slice);
        vfloat4 o;
        o.x = xv.x * cs.x - xv.y * cs.y;
        o.y = xv.x * cs.y + xv.y * cs.x;
        o.z = xv.z * cs.z - xv.w * cs.w;
        o.w = xv.z * cs.w + xv.w * cs.z;
        __builtin_nontemporal_store(o, reinterpret_cast<vfloat4*>(ob + (size_t)k * ostep));
    }
}

// ---- fallback (R2 kernel) if ws too small ----
__global__ __launch_bounds__(256) void rope_gather_kernel(
        const float* __restrict__ x,
        const float* __restrict__ rope,
        const int* __restrict__ tp,
        float* __restrict__ out) {
    const int s = blockIdx.x;
    const int p = tp[s];
    const int q = threadIdx.x & 31;
    const int g = threadIdx.x >> 5;

    const float* rp = rope + (size_t)p * (DK * DK);
    const int i0 = q << 1;
    const float2 cs0 = *reinterpret_cast<const float2*>(rp + (size_t)258 * i0);
    const float2 cs1 = *reinterpret_cast<const float2*>(rp + (size_t)258 * (i0 + 1));

    const size_t rowstride = (size_t)SEQL * DK;
    const size_t xbase = (size_t)p * DK + (q << 2);
    const size_t obase = (size_t)s * DK + (q << 2);

    #pragma unroll
    for (int bh = g; bh < NBH; bh += 8) {
        const float4 xv = *reinterpret_cast<const float4*>(x + xbase + (size_t)bh * rowstride);
        float4 o;
        o.x = xv.x * cs0.x - xv.y * cs0.y;
        o.y = xv.x * cs0.y + xv.y * cs0.x;
        o.z = xv.z * cs1.x - xv.w * cs1.y;
        o.w = xv.z * cs1.y + xv.w * cs1.x;
        *reinterpret_cast<float4*>(out + obase + (size_t)bh * rowstride) = o;
    }
}

extern "C" void kernel_launch(void* const* d_in, const int* in_sizes, int n_in,
                              void* d_out, int out_size, void* d_ws, size_t ws_size,
                              hipStream_t stream) {
    const float* x    = (const float*)d_in[0];
    const float* rope = (const float*)d_in[1];
    const int*   tp   = (const int*)d_in[2];
    float*       out  = (float*)d_out;

    const size_t need = (size_t)SEQL * (DK / 2) * sizeof(float2);  // 1 MB
    if (ws_size < need) {
        rope_gather_kernel<<<SEQL, 256, 0, stream>>>(x, rope, tp, out);
        return;
    }

    float2* cstab = (float2*)d_ws;
    build_cs_kernel<<<SEQL * (DK / 2) / 256, 256, 0, stream>>>(rope, tp, cstab);
    rope_flat_kernel<<<NBLK, BLK, 0, stream>>>(x, cstab, tp, out);
}

// Round 6
// 29.915 us; speedup vs baseline: 1.0929x; 1.0396x over previous
//
#include <hip/hip_runtime.h>

// RoPE with position gather — fused single-kernel, output-streaming.
// x:    [B=4, H=16, S=2048, D=128] f32
// rope: [4096, 128, 128] f32 (only the 2x2 rotation diagonals are read)
// tp:   [2048] int32;  out[b,h,s,:] = rotate(x[b,h,p,:], angles(p)), p=tp[s]
//
// cos(p,i) = rope[p*16384 + 258*i], sin = +1.
//
// Flat over out in memory order -> writes perfectly streaming (nt-store).
// Grid-stride of 8 iters lands on the SAME s each iter (stride is a multiple
// of 2048 rows), so tp and the two cos/sin float2s are loaded ONCE per thread
// and reused across 8 independent gathered x-loads + 8 contiguous stores.
// cs duplicates across threads hit L2/MALL (~5 MB distinct lines).

#define SEQL 2048
#define DK   128
#define BLK  256
#define NBLK 2048
#define ITER 8             // 64*2048*(128/4) quads / (NBLK*BLK)

typedef float vfloat4 __attribute__((ext_vector_type(4)));

__global__ __launch_bounds__(BLK) void rope_fused_kernel(
        const float* __restrict__ x,
        const float* __restrict__ rope,
        const int* __restrict__ tp,
        float* __restrict__ out) {
    const int idx0 = blockIdx.x * BLK + threadIdx.x;
    const int row0 = idx0 >> 5;            // bh0*SEQL + s
    const int q    = idx0 & 31;            // float4-quad within 128-elem row
    const int s    = row0 & (SEQL - 1);    // constant across iters
    const int bh0  = row0 >> 11;           // 0..7
    const int p    = tp[s];

    const float* rp = rope + (size_t)p * (DK * DK);
    const int i0 = q << 1;
    const float2 cs0 = *reinterpret_cast<const float2*>(rp + (size_t)258 * i0);
    const float2 cs1 = *reinterpret_cast<const float2*>(rp + (size_t)258 * (i0 + 1));

    const size_t slice = (size_t)SEQL * DK;             // bh stride (elems)
    const float* xb = x + (size_t)p * DK + (q << 2);
    float* ob = out + (size_t)idx0 * 4;                 // contiguous per wave
    const size_t ostep = (size_t)NBLK * BLK * 4;        // 8 bh slices ahead

    #pragma unroll
    for (int k = 0; k < ITER; ++k) {
        const float4 xv = *reinterpret_cast<const float4*>(xb + (size_t)(bh0 + 8 * k) * slice);
        vfloat4 o;
        o.x = xv.x * cs0.x - xv.y * cs0.y;
        o.y = xv.x * cs0.y + xv.y * cs0.x;
        o.z = xv.z * cs1.x - xv.w * cs1.y;
        o.w = xv.z * cs1.y + xv.w * cs1.x;
        __builtin_nontemporal_store(o, reinterpret_cast<vfloat4*>(ob + (size_t)k * ostep));
    }
}

extern "C" void kernel_launch(void* const* d_in, const int* in_sizes, int n_in,
                              void* d_out, int out_size, void* d_ws, size_t ws_size,
                              hipStream_t stream) {
    const float* x    = (const float*)d_in[0];
    const float* rope = (const float*)d_in[1];
    const int*   tp   = (const int*)d_in[2];
    float*       out  = (float*)d_out;

    rope_fused_kernel<<<NBLK, BLK, 0, stream>>>(x, rope, tp, out);
}

// Round 7
// 27.431 us; speedup vs baseline: 1.1919x; 1.0906x over previous
//
#include <hip/hip_runtime.h>

// RoPE with position gather — fused, output-streaming, low-replication shape.
// x:    [B=4, H=16, S=2048, D=128] f32
// rope: [4096, 128, 128] f32 (only the 2x2 rotation diagonals are read)
// tp:   [2048] int32;  out[b,h,s,:] = rotate(x[b,h,p,:], angles(p)), p=tp[s]
//
// 512 blocks x 256 thr; thread owns (s, q, bh0 in {0,1}) and iterates 32 bh
// slices (bh = bh0 + 2k). Scattered cs float2 loads: 2 per thread = 256K
// requests total (4x fewer than the 2048-block shape); tp loads 128K.
// Writes remain perfectly streaming nt-stores; 8-deep unroll keeps ~8
// independent float4 loads in flight per thread (8 waves/CU x 8 = 64/CU).

#define SEQL 2048
#define DK   128
#define BLK  256
#define NBLK 512
#define ITER 32            // 64*2048*(128/4) quads / (NBLK*BLK)

typedef float vfloat4 __attribute__((ext_vector_type(4)));

__global__ __launch_bounds__(BLK) void rope_fused_kernel(
        const float* __restrict__ x,
        const float* __restrict__ rope,
        const int* __restrict__ tp,
        float* __restrict__ out) {
    const int idx0 = blockIdx.x * BLK + threadIdx.x;
    const int row0 = idx0 >> 5;            // bh0*SEQL + s  (row0 in [0,4096))
    const int q    = idx0 & 31;            // float4-quad within 128-elem row
    const int s    = row0 & (SEQL - 1);    // constant across iters
    const int bh0  = row0 >> 11;           // 0..1
    const int p    = tp[s];

    const float* rp = rope + (size_t)p * (DK * DK);
    const int i0 = q << 1;
    const float2 cs0 = *reinterpret_cast<const float2*>(rp + (size_t)258 * i0);
    const float2 cs1 = *reinterpret_cast<const float2*>(rp + (size_t)258 * (i0 + 1));

    const size_t slice = (size_t)SEQL * DK;             // bh stride (elems)
    const float* xb = x + (size_t)p * DK + (q << 2) + (size_t)bh0 * slice;
    float* ob = out + (size_t)idx0 * 4;                 // contiguous per wave
    const size_t ostep = (size_t)NBLK * BLK * 4;        // elems between iters

    #pragma unroll 8
    for (int k = 0; k < ITER; ++k) {
        const float4 xv = *reinterpret_cast<const float4*>(xb + (size_t)(2 * k) * slice);
        vfloat4 o;
        o.x = xv.x * cs0.x - xv.y * cs0.y;
        o.y = xv.x * cs0.y + xv.y * cs0.x;
        o.z = xv.z * cs1.x - xv.w * cs1.y;
        o.w = xv.z * cs1.y + xv.w * cs1.x;
        __builtin_nontemporal_store(o, reinterpret_cast<vfloat4*>(ob + (size_t)k * ostep));
    }
}

extern "C" void kernel_launch(void* const* d_in, const int* in_sizes, int n_in,
                              void* d_out, int out_size, void* d_ws, size_t ws_size,
                              hipStream_t stream) {
    const float* x    = (const float*)d_in[0];
    const float* rope = (const float*)d_in[1];
    const int*   tp   = (const int*)d_in[2];
    float*       out  = (float*)d_out;

    rope_fused_kernel<<<NBLK, BLK, 0, stream>>>(x, rope, tp, out);
}

// Round 8
// 26.671 us; speedup vs baseline: 1.2259x; 1.0285x over previous
//
#include <hip/hip_runtime.h>

// RoPE with position gather — fused, output-streaming, 1x-replication shape.
// x:    [B=4, H=16, S=2048, D=128] f32
// rope: [4096, 128, 128] f32 (only the 2x2 rotation diagonals are read)
// tp:   [2048] int32;  out[b,h,s,:] = rotate(x[b,h,p,:], angles(p)), p=tp[s]
//
// 65536 threads (512 x 128): thread owns ONE unique (s, q) and iterates all
// 64 bh slices. Scattered cs float2 loads: exactly 2 per (s,q) = 128K total
// (minimum possible without cross-block sharing); tp loads 64K. Writes
// remain perfectly streaming (each iter writes one contiguous bh slice).
// unroll 16 -> 16 independent gathered float4 loads in flight per thread
// to cover the lower occupancy (4 waves/CU).

#define SEQL 2048
#define DK   128
#define BLK  128
#define NBLK 512
#define ITER 64            // all bh slices per thread

typedef float vfloat4 __attribute__((ext_vector_type(4)));

__global__ __launch_bounds__(BLK) void rope_fused_kernel(
        const float* __restrict__ x,
        const float* __restrict__ rope,
        const int* __restrict__ tp,
        float* __restrict__ out) {
    const int idx0 = blockIdx.x * BLK + threadIdx.x;   // = s*32 + q, unique
    const int q    = idx0 & 31;            // float4-quad within 128-elem row
    const int s    = idx0 >> 5;            // 0..2047
    const int p    = tp[s];

    const float* rp = rope + (size_t)p * (DK * DK);
    const int i0 = q << 1;
    const float2 cs0 = *reinterpret_cast<const float2*>(rp + (size_t)258 * i0);
    const float2 cs1 = *reinterpret_cast<const float2*>(rp + (size_t)258 * (i0 + 1));

    const size_t slice = (size_t)SEQL * DK;             // bh stride (elems)
    const float* xb = x + (size_t)p * DK + (q << 2);
    float* ob = out + (size_t)idx0 * 4;                 // contiguous per wave
    const size_t ostep = (size_t)NBLK * BLK * 4;        // = one bh slice

    #pragma unroll 16
    for (int k = 0; k < ITER; ++k) {
        const float4 xv = *reinterpret_cast<const float4*>(xb + (size_t)k * slice);
        vfloat4 o;
        o.x = xv.x * cs0.x - xv.y * cs0.y;
        o.y = xv.x * cs0.y + xv.y * cs0.x;
        o.z = xv.z * cs1.x - xv.w * cs1.y;
        o.w = xv.z * cs1.y + xv.w * cs1.x;
        __builtin_nontemporal_store(o, reinterpret_cast<vfloat4*>(ob + (size_t)k * ostep));
    }
}

extern "C" void kernel_launch(void* const* d_in, const int* in_sizes, int n_in,
                              void* d_out, int out_size, void* d_ws, size_t ws_size,
                              hipStream_t stream) {
    const float* x    = (const float*)d_in[0];
    const float* rope = (const float*)d_in[1];
    const int*   tp   = (const int*)d_in[2];
    float*       out  = (float*)d_out;

    rope_fused_kernel<<<NBLK, BLK, 0, stream>>>(x, rope, tp, out);
}